// Round 4
// baseline (161.064 us; speedup 1.0000x reference)
//
#include <hip/hip_runtime.h>

typedef unsigned short u16;
typedef unsigned int   u32;
typedef __attribute__((ext_vector_type(8))) short bf16x8;
typedef __attribute__((ext_vector_type(4))) float f32x4;

__device__ __forceinline__ float bf2f(u16 h) { return __uint_as_float(((u32)h) << 16); }
__device__ __forceinline__ u16 f2bf(float f) {
    u32 u = __float_as_uint(f);
    return (u16)((u + 0x7fffu + ((u >> 16) & 1u)) >> 16);
}

constexpr int QK_STR = 40;   // halfwords per q/k row  (mult of 8 for b128, banks spread)
constexpr int VT_STR = 72;   // halfwords per vT row
constexpr int P_STR  = 72;   // halfwords per P row
constexpr int O_STR  = 136;  // halfwords per o_s row

// workspace (u16 elems): [0,49152) qkv_w bf16 ; [49152,65536) proj_w bf16 ;
//                        [65536,131072) fused bias+mask bf16 [cls4][h4][64][64]
__global__ void prep_kernel(const float* __restrict__ qkv_w,
                            const float* __restrict__ proj_w,
                            const float* __restrict__ mask,
                            const float* __restrict__ rpb,
                            const int*   __restrict__ rel,
                            u16* __restrict__ ws)
{
    int i = blockIdx.x * 256 + threadIdx.x;
    if (i < 49152) ws[i] = f2bf(qkv_w[i]);
    if (i < 16384) ws[49152 + i] = f2bf(proj_w[i]);
    if (i < 65536) {
        int m = i & 63, r = (i >> 6) & 63, h = (i >> 12) & 3, cls = i >> 14;
        float v;
        if (m >= 49)      v = -30000.f;   // kill padded K-tokens: exp underflows to exact 0
        else if (r >= 49) v = 0.f;        // padded Q-rows: value irrelevant, keep finite
        else {
            int rep = ((cls & 2) ? 240 : 0) + ((cls & 1) ? 15 : 0);  // representative window
            v = rpb[rel[r * 49 + m] * 4 + h] + mask[(rep * 49 + r) * 49 + m];
        }
        ws[65536 + i] = f2bf(v);
    }
}

__global__ __launch_bounds__(512, 2)
void swin_mfma(const float* __restrict__ x,
               const float* __restrict__ qkv_b,
               const float* __restrict__ proj_b,
               const u16*   __restrict__ wqkv,
               const u16*   __restrict__ wproj,
               const u16*   __restrict__ fused,
               float* __restrict__ out)
{
    __shared__ u16 q_s[4 * 64 * QK_STR];   // 20480 B
    __shared__ u16 k_s[4 * 64 * QK_STR];   // 20480 B
    __shared__ u16 vT_s[4 * 32 * VT_STR];  // 18432 B
    __shared__ u16 p_s[8 * 16 * P_STR];    // 18432 B (per-wave P rows)
    __shared__ u16 o_s[64 * O_STR];        // 17408 B

    const int tid  = threadIdx.x;
    const int w    = tid >> 6;          // wave 0..7
    const int lane = tid & 63;
    const int lr   = lane & 15;         // frag row/col index
    const int lg   = lane >> 4;         // frag k-group 0..3
    const int bid  = blockIdx.x;
    const int b    = bid >> 8;
    const int wi   = bid & 255;
    const int wh   = wi >> 4, ww = wi & 15;
    const int cls  = ((wh == 15) ? 2 : 0) | ((ww == 15) ? 1 : 0);

    // ---------------- stage 1: QKV GEMM, x read as A-frags from global ----------------
    bf16x8 a[4][4];
#pragma unroll
    for (int mt2 = 0; mt2 < 4; ++mt2) {
        int tok = mt2 * 16 + lr;
        int tr = tok / 7, tc = tok - tr * 7;
        int hs = wh * 7 + tr + 3; if (hs >= 112) hs -= 112;
        int cs = ww * 7 + tc + 3; if (cs >= 112) cs -= 112;
        int xbase = ((b * 112 + hs) * 112 + cs) * 128;
        bool valid = tok < 49;
#pragma unroll
        for (int kt = 0; kt < 4; ++kt) {
            bf16x8 f = {0, 0, 0, 0, 0, 0, 0, 0};
            if (valid) {
                const float4* xp = (const float4*)&x[xbase + kt * 32 + lg * 8];
                float4 x0 = xp[0], x1 = xp[1];
                f[0] = f2bf(x0.x); f[1] = f2bf(x0.y); f[2] = f2bf(x0.z); f[3] = f2bf(x0.w);
                f[4] = f2bf(x1.x); f[5] = f2bf(x1.y); f[6] = f2bf(x1.z); f[7] = f2bf(x1.w);
            }
            a[mt2][kt] = f;
        }
    }

#pragma unroll
    for (int t = 0; t < 3; ++t) {
        int n0 = w * 48 + t * 16;                 // output-channel tile base (uniform per wave)
        bf16x8 bw[4];
#pragma unroll
        for (int kt = 0; kt < 4; ++kt)
            bw[kt] = *(const bf16x8*)&wqkv[(n0 + lr) * 128 + kt * 32 + lg * 8];
        float bias = qkv_b[n0 + lr];
        int which = n0 >> 7;                      // 0=q 1=k 2=v (uniform)
        int h = (n0 & 127) >> 5;                  // head (uniform)
        int d = (n0 & 31) + lr;                   // dim within head
#pragma unroll
        for (int mt2 = 0; mt2 < 4; ++mt2) {
            f32x4 acc = {0.f, 0.f, 0.f, 0.f};
#pragma unroll
            for (int kt = 0; kt < 4; ++kt)
                acc = __builtin_amdgcn_mfma_f32_16x16x32_bf16(a[mt2][kt], bw[kt], acc, 0, 0, 0);
            if (which == 0) {
#pragma unroll
                for (int j = 0; j < 4; ++j)
                    q_s[(h * 64 + mt2 * 16 + lg * 4 + j) * QK_STR + d] =
                        f2bf((acc[j] + bias) * 0.17677669529663687f);
            } else if (which == 1) {
#pragma unroll
                for (int j = 0; j < 4; ++j)
                    k_s[(h * 64 + mt2 * 16 + lg * 4 + j) * QK_STR + d] = f2bf(acc[j] + bias);
            } else {
                ushort4 pk;
                pk.x = f2bf(acc[0] + bias); pk.y = f2bf(acc[1] + bias);
                pk.z = f2bf(acc[2] + bias); pk.w = f2bf(acc[3] + bias);
                *(ushort4*)&vT_s[(h * 32 + d) * VT_STR + mt2 * 16 + lg * 4] = pk;  // V transposed
            }
        }
    }
    __syncthreads();  // the only block-wide barrier before proj

    // ---------------- stage 2: attention; wave -> (M-tile, head-pair) ----------------
    const int mt = w & 3, hp = w >> 2;
    float invs[2][4];
#pragma unroll
    for (int hl = 0; hl < 2; ++hl) {
        int h = hp * 2 + hl;
        bf16x8 aq = *(const bf16x8*)&q_s[(h * 64 + mt * 16 + lr) * QK_STR + lg * 8];
        f32x4 sc[4];
#pragma unroll
        for (int nt = 0; nt < 4; ++nt) {
            bf16x8 bk = *(const bf16x8*)&k_s[(h * 64 + nt * 16 + lr) * QK_STR + lg * 8];
            f32x4 z = {0.f, 0.f, 0.f, 0.f};
            sc[nt] = __builtin_amdgcn_mfma_f32_16x16x32_bf16(aq, bk, z, 0, 0, 0);
        }
        float s[4][4];
        const u16* ft = &fused[((cls * 4 + h) * 64 + mt * 16) * 64];
#pragma unroll
        for (int j = 0; j < 4; ++j)
#pragma unroll
            for (int nt = 0; nt < 4; ++nt)
                s[nt][j] = sc[nt][j] + bf2f(ft[(lg * 4 + j) * 64 + nt * 16 + lr]);
#pragma unroll
        for (int j = 0; j < 4; ++j) {
            float mx = fmaxf(fmaxf(s[0][j], s[1][j]), fmaxf(s[2][j], s[3][j]));
            mx = fmaxf(mx, __shfl_xor(mx, 1));
            mx = fmaxf(mx, __shfl_xor(mx, 2));
            mx = fmaxf(mx, __shfl_xor(mx, 4));
            mx = fmaxf(mx, __shfl_xor(mx, 8));
            float p0 = __expf(s[0][j] - mx), p1 = __expf(s[1][j] - mx);
            float p2 = __expf(s[2][j] - mx), p3 = __expf(s[3][j] - mx);
            float sm = p0 + p1 + p2 + p3;
            sm += __shfl_xor(sm, 1);
            sm += __shfl_xor(sm, 2);
            sm += __shfl_xor(sm, 4);
            sm += __shfl_xor(sm, 8);
            invs[hl][j] = 1.f / sm;   // sum >= 1 always (max term is 1)
            u16* pr = &p_s[(w * 16 + lg * 4 + j) * P_STR];
            pr[lr]      = f2bf(p0);
            pr[16 + lr] = f2bf(p1);
            pr[32 + lr] = f2bf(p2);
            pr[48 + lr] = f2bf(p3);
        }
        // PV: A = P (own rows), B = vT
        bf16x8 ap0 = *(const bf16x8*)&p_s[(w * 16 + lr) * P_STR + lg * 8];
        bf16x8 ap1 = *(const bf16x8*)&p_s[(w * 16 + lr) * P_STR + 32 + lg * 8];
#pragma unroll
        for (int nt = 0; nt < 2; ++nt) {
            bf16x8 bv0 = *(const bf16x8*)&vT_s[(h * 32 + nt * 16 + lr) * VT_STR + lg * 8];
            bf16x8 bv1 = *(const bf16x8*)&vT_s[(h * 32 + nt * 16 + lr) * VT_STR + 32 + lg * 8];
            f32x4 z = {0.f, 0.f, 0.f, 0.f};
            f32x4 o = __builtin_amdgcn_mfma_f32_16x16x32_bf16(ap0, bv0, z, 0, 0, 0);
            o = __builtin_amdgcn_mfma_f32_16x16x32_bf16(ap1, bv1, o, 0, 0, 0);
#pragma unroll
            for (int j = 0; j < 4; ++j)
                o_s[(mt * 16 + lg * 4 + j) * O_STR + h * 32 + nt * 16 + lr] =
                    f2bf(o[j] * invs[hl][j]);
        }
    }
    __syncthreads();  // o_s columns cross heads written by two waves per row-tile

    // ---------------- stage 3: proj; wave -> (M-tile mt, N-half hp) ----------------
    bf16x8 ao[4];
#pragma unroll
    for (int kt = 0; kt < 4; ++kt)
        ao[kt] = *(const bf16x8*)&o_s[(mt * 16 + lr) * O_STR + kt * 32 + lg * 8];
    int obase[4];
#pragma unroll
    for (int j = 0; j < 4; ++j) {
        int tok = mt * 16 + lg * 4 + j;
        if (tok < 49) {
            int tr = tok / 7, tc = tok - tr * 7;
            int hs = wh * 7 + tr + 3; if (hs >= 112) hs -= 112;
            int cs = ww * 7 + tc + 3; if (cs >= 112) cs -= 112;
            obase[j] = ((b * 112 + hs) * 112 + cs) * 128;
        } else obase[j] = -1;
    }
#pragma unroll
    for (int tn = 0; tn < 4; ++tn) {
        int n0 = (hp * 4 + tn) * 16;
        bf16x8 bw[4];
#pragma unroll
        for (int kt = 0; kt < 4; ++kt)
            bw[kt] = *(const bf16x8*)&wproj[(n0 + lr) * 128 + kt * 32 + lg * 8];
        f32x4 acc = {0.f, 0.f, 0.f, 0.f};
#pragma unroll
        for (int kt = 0; kt < 4; ++kt)
            acc = __builtin_amdgcn_mfma_f32_16x16x32_bf16(ao[kt], bw[kt], acc, 0, 0, 0);
        float bias = proj_b[n0 + lr];
#pragma unroll
        for (int j = 0; j < 4; ++j)
            if (obase[j] >= 0) out[obase[j] + n0 + lr] = acc[j] + bias;
    }
}

extern "C" void kernel_launch(void* const* d_in, const int* in_sizes, int n_in,
                              void* d_out, int out_size, void* d_ws, size_t ws_size,
                              hipStream_t stream) {
    (void)in_sizes; (void)n_in; (void)out_size; (void)ws_size;
    const float* x      = (const float*)d_in[0];
    const float* mask   = (const float*)d_in[1];
    const float* qkv_w  = (const float*)d_in[2];
    const float* qkv_b  = (const float*)d_in[3];
    const float* proj_w = (const float*)d_in[4];
    const float* proj_b = (const float*)d_in[5];
    const float* rpb    = (const float*)d_in[6];
    const int*   rel    = (const int*)d_in[7];
    float* out = (float*)d_out;

    u16* ws16 = (u16*)d_ws;
    prep_kernel<<<dim3(256), dim3(256), 0, stream>>>(qkv_w, proj_w, mask, rpb, rel, ws16);
    swin_mfma<<<dim3(2048), dim3(512), 0, stream>>>(
        x, qkv_b, proj_b, ws16, ws16 + 49152, ws16 + 65536, out);
}

// Round 5
// 160.559 us; speedup vs baseline: 1.0031x; 1.0031x over previous
//
#include <hip/hip_runtime.h>

typedef unsigned short u16;
typedef unsigned int   u32;
typedef __attribute__((ext_vector_type(8))) short bf16x8;
typedef __attribute__((ext_vector_type(4))) float f32x4;

__device__ __forceinline__ float bf2f(u16 h) { return __uint_as_float(((u32)h) << 16); }
__device__ __forceinline__ u16 f2bf(float f) {
    u32 u = __float_as_uint(f);
    return (u16)((u + 0x7fffu + ((u >> 16) & 1u)) >> 16);
}

constexpr int QK_STR = 40;   // halfwords per q/k row  (mult of 8 for b128, banks spread)
constexpr int VT_STR = 72;   // halfwords per vT row
constexpr int P_STR  = 72;   // halfwords per P row
constexpr int O_STR  = 136;  // halfwords per o_s row

// workspace (u16 elems): [0,49152) qkv_w bf16 ; [49152,65536) proj_w bf16 ;
//                        [65536,131072) fused bias+mask bf16 [cls4][h4][64][64]
__global__ void prep_kernel(const float* __restrict__ qkv_w,
                            const float* __restrict__ proj_w,
                            const float* __restrict__ mask,
                            const float* __restrict__ rpb,
                            const int*   __restrict__ rel,
                            u16* __restrict__ ws)
{
    int i = blockIdx.x * 256 + threadIdx.x;
    if (i < 49152) ws[i] = f2bf(qkv_w[i]);
    if (i < 16384) ws[49152 + i] = f2bf(proj_w[i]);
    if (i < 65536) {
        int m = i & 63, r = (i >> 6) & 63, h = (i >> 12) & 3, cls = i >> 14;
        float v;
        if (m >= 49)      v = -30000.f;   // kill padded K-tokens: exp underflows to exact 0
        else if (r >= 49) v = 0.f;        // padded Q-rows: value irrelevant, keep finite
        else {
            int rep = ((cls & 2) ? 240 : 0) + ((cls & 1) ? 15 : 0);  // representative window
            v = rpb[rel[r * 49 + m] * 4 + h] + mask[(rep * 49 + r) * 49 + m];
        }
        ws[65536 + i] = f2bf(v);
    }
}

__global__ __launch_bounds__(512, 2)
void swin_mfma(const float* __restrict__ x,
               const float* __restrict__ qkv_b,
               const float* __restrict__ proj_b,
               const u16*   __restrict__ wqkv,
               const u16*   __restrict__ wproj,
               const u16*   __restrict__ fused,
               float* __restrict__ out)
{
    __shared__ u16 q_s[4 * 64 * QK_STR];   // 20480 B
    __shared__ u16 k_s[4 * 64 * QK_STR];   // 20480 B
    __shared__ u16 vT_s[4 * 32 * VT_STR];  // 18432 B
    __shared__ u16 p_s[8 * 16 * P_STR];    // 18432 B (per-wave P rows)
    __shared__ u16 o_s[64 * O_STR];        // 17408 B

    const int tid  = threadIdx.x;
    const int w    = tid >> 6;          // wave 0..7
    const int lane = tid & 63;
    const int lr   = lane & 15;         // frag row/col index
    const int lg   = lane >> 4;         // frag k-group 0..3
    const int bid  = blockIdx.x;
    const int b    = bid >> 8;
    const int wi   = bid & 255;
    const int wh   = wi >> 4, ww = wi & 15;
    const int cls  = ((wh == 15) ? 2 : 0) | ((ww == 15) ? 1 : 0);

    // ---------------- stage 1: QKV GEMM, x read as A-frags from global ----------------
    bf16x8 a[4][4];
#pragma unroll
    for (int mt2 = 0; mt2 < 4; ++mt2) {
        int tok = mt2 * 16 + lr;
        int tr = tok / 7, tc = tok - tr * 7;
        int hs = wh * 7 + tr + 3; if (hs >= 112) hs -= 112;
        int cs = ww * 7 + tc + 3; if (cs >= 112) cs -= 112;
        int xbase = ((b * 112 + hs) * 112 + cs) * 128;
        bool valid = tok < 49;
#pragma unroll
        for (int kt = 0; kt < 4; ++kt) {
            bf16x8 f = {0, 0, 0, 0, 0, 0, 0, 0};
            if (valid) {
                const float4* xp = (const float4*)&x[xbase + kt * 32 + lg * 8];
                float4 x0 = xp[0], x1 = xp[1];
                f[0] = f2bf(x0.x); f[1] = f2bf(x0.y); f[2] = f2bf(x0.z); f[3] = f2bf(x0.w);
                f[4] = f2bf(x1.x); f[5] = f2bf(x1.y); f[6] = f2bf(x1.z); f[7] = f2bf(x1.w);
            }
            a[mt2][kt] = f;
        }
    }

#pragma unroll
    for (int t = 0; t < 3; ++t) {
        int n0 = w * 48 + t * 16;                 // output-channel tile base (uniform per wave)
        bf16x8 bw[4];
#pragma unroll
        for (int kt = 0; kt < 4; ++kt)
            bw[kt] = *(const bf16x8*)&wqkv[(n0 + lr) * 128 + kt * 32 + lg * 8];
        float bias = qkv_b[n0 + lr];
        int which = n0 >> 7;                      // 0=q 1=k 2=v (uniform)
        int h = (n0 & 127) >> 5;                  // head (uniform)
        int d = (n0 & 31) + lr;                   // dim within head
#pragma unroll
        for (int mt2 = 0; mt2 < 4; ++mt2) {
            f32x4 acc = {0.f, 0.f, 0.f, 0.f};
#pragma unroll
            for (int kt = 0; kt < 4; ++kt)
                acc = __builtin_amdgcn_mfma_f32_16x16x32_bf16(a[mt2][kt], bw[kt], acc, 0, 0, 0);
            if (which == 0) {
#pragma unroll
                for (int j = 0; j < 4; ++j)
                    q_s[(h * 64 + mt2 * 16 + lg * 4 + j) * QK_STR + d] =
                        f2bf((acc[j] + bias) * 0.17677669529663687f);
            } else if (which == 1) {
#pragma unroll
                for (int j = 0; j < 4; ++j)
                    k_s[(h * 64 + mt2 * 16 + lg * 4 + j) * QK_STR + d] = f2bf(acc[j] + bias);
            } else {
                ushort4 pk;
                pk.x = f2bf(acc[0] + bias); pk.y = f2bf(acc[1] + bias);
                pk.z = f2bf(acc[2] + bias); pk.w = f2bf(acc[3] + bias);
                *(ushort4*)&vT_s[(h * 32 + d) * VT_STR + mt2 * 16 + lg * 4] = pk;  // V transposed
            }
        }
    }
    __syncthreads();  // the only block-wide barrier before proj

    // ---------------- stage 2: attention; wave -> (M-tile, head-pair) ----------------
    const int mt = w & 3, hp = w >> 2;
    float invs[2][4];
#pragma unroll
    for (int hl = 0; hl < 2; ++hl) {
        int h = hp * 2 + hl;
        bf16x8 aq = *(const bf16x8*)&q_s[(h * 64 + mt * 16 + lr) * QK_STR + lg * 8];
        f32x4 sc[4];
#pragma unroll
        for (int nt = 0; nt < 4; ++nt) {
            bf16x8 bk = *(const bf16x8*)&k_s[(h * 64 + nt * 16 + lr) * QK_STR + lg * 8];
            f32x4 z = {0.f, 0.f, 0.f, 0.f};
            sc[nt] = __builtin_amdgcn_mfma_f32_16x16x32_bf16(aq, bk, z, 0, 0, 0);
        }
        float s[4][4];
        const u16* ft = &fused[((cls * 4 + h) * 64 + mt * 16) * 64];
#pragma unroll
        for (int j = 0; j < 4; ++j)
#pragma unroll
            for (int nt = 0; nt < 4; ++nt)
                s[nt][j] = sc[nt][j] + bf2f(ft[(lg * 4 + j) * 64 + nt * 16 + lr]);
#pragma unroll
        for (int j = 0; j < 4; ++j) {
            float mx = fmaxf(fmaxf(s[0][j], s[1][j]), fmaxf(s[2][j], s[3][j]));
            mx = fmaxf(mx, __shfl_xor(mx, 1));
            mx = fmaxf(mx, __shfl_xor(mx, 2));
            mx = fmaxf(mx, __shfl_xor(mx, 4));
            mx = fmaxf(mx, __shfl_xor(mx, 8));
            float p0 = __expf(s[0][j] - mx), p1 = __expf(s[1][j] - mx);
            float p2 = __expf(s[2][j] - mx), p3 = __expf(s[3][j] - mx);
            float sm = p0 + p1 + p2 + p3;
            sm += __shfl_xor(sm, 1);
            sm += __shfl_xor(sm, 2);
            sm += __shfl_xor(sm, 4);
            sm += __shfl_xor(sm, 8);
            invs[hl][j] = 1.f / sm;   // sum >= 1 always (max term is 1)
            u16* pr = &p_s[(w * 16 + lg * 4 + j) * P_STR];
            pr[lr]      = f2bf(p0);
            pr[16 + lr] = f2bf(p1);
            pr[32 + lr] = f2bf(p2);
            pr[48 + lr] = f2bf(p3);
        }
        // PV: A = P (own rows), B = vT
        bf16x8 ap0 = *(const bf16x8*)&p_s[(w * 16 + lr) * P_STR + lg * 8];
        bf16x8 ap1 = *(const bf16x8*)&p_s[(w * 16 + lr) * P_STR + 32 + lg * 8];
#pragma unroll
        for (int nt = 0; nt < 2; ++nt) {
            bf16x8 bv0 = *(const bf16x8*)&vT_s[(h * 32 + nt * 16 + lr) * VT_STR + lg * 8];
            bf16x8 bv1 = *(const bf16x8*)&vT_s[(h * 32 + nt * 16 + lr) * VT_STR + 32 + lg * 8];
            f32x4 z = {0.f, 0.f, 0.f, 0.f};
            f32x4 o = __builtin_amdgcn_mfma_f32_16x16x32_bf16(ap0, bv0, z, 0, 0, 0);
            o = __builtin_amdgcn_mfma_f32_16x16x32_bf16(ap1, bv1, o, 0, 0, 0);
#pragma unroll
            for (int j = 0; j < 4; ++j)
                o_s[(mt * 16 + lg * 4 + j) * O_STR + h * 32 + nt * 16 + lr] =
                    f2bf(o[j] * invs[hl][j]);
        }
    }
    __syncthreads();  // o_s columns cross heads written by two waves per row-tile

    // ---------------- stage 3: proj; wave -> (M-tile mt, N-half hp) ----------------
    bf16x8 ao[4];
#pragma unroll
    for (int kt = 0; kt < 4; ++kt)
        ao[kt] = *(const bf16x8*)&o_s[(mt * 16 + lr) * O_STR + kt * 32 + lg * 8];
    int obase[4];
#pragma unroll
    for (int j = 0; j < 4; ++j) {
        int tok = mt * 16 + lg * 4 + j;
        if (tok < 49) {
            int tr = tok / 7, tc = tok - tr * 7;
            int hs = wh * 7 + tr + 3; if (hs >= 112) hs -= 112;
            int cs = ww * 7 + tc + 3; if (cs >= 112) cs -= 112;
            obase[j] = ((b * 112 + hs) * 112 + cs) * 128;
        } else obase[j] = -1;
    }
#pragma unroll
    for (int tn = 0; tn < 4; ++tn) {
        int n0 = (hp * 4 + tn) * 16;
        bf16x8 bw[4];
#pragma unroll
        for (int kt = 0; kt < 4; ++kt)
            bw[kt] = *(const bf16x8*)&wproj[(n0 + lr) * 128 + kt * 32 + lg * 8];
        f32x4 acc = {0.f, 0.f, 0.f, 0.f};
#pragma unroll
        for (int kt = 0; kt < 4; ++kt)
            acc = __builtin_amdgcn_mfma_f32_16x16x32_bf16(ao[kt], bw[kt], acc, 0, 0, 0);
        float bias = proj_b[n0 + lr];
#pragma unroll
        for (int j = 0; j < 4; ++j)
            if (obase[j] >= 0) out[obase[j] + n0 + lr] = acc[j] + bias;
    }
}

extern "C" void kernel_launch(void* const* d_in, const int* in_sizes, int n_in,
                              void* d_out, int out_size, void* d_ws, size_t ws_size,
                              hipStream_t stream) {
    (void)in_sizes; (void)n_in; (void)out_size; (void)ws_size;
    const float* x      = (const float*)d_in[0];
    const float* mask   = (const float*)d_in[1];
    const float* qkv_w  = (const float*)d_in[2];
    const float* qkv_b  = (const float*)d_in[3];
    const float* proj_w = (const float*)d_in[4];
    const float* proj_b = (const float*)d_in[5];
    const float* rpb    = (const float*)d_in[6];
    const int*   rel    = (const int*)d_in[7];
    float* out = (float*)d_out;

    u16* ws16 = (u16*)d_ws;
    prep_kernel<<<dim3(256), dim3(256), 0, stream>>>(qkv_w, proj_w, mask, rpb, rel, ws16);
    swin_mfma<<<dim3(2048), dim3(512), 0, stream>>>(
        x, qkv_b, proj_b, ws16, ws16 + 49152, ws16 + 65536, out);
}